// Round 17
// baseline (471.427 us; speedup 1.0000x reference)
//
#include <hip/hip_runtime.h>

#define DEV __device__ __forceinline__

typedef __attribute__((ext_vector_type(4))) float f32x4;
typedef __attribute__((ext_vector_type(8))) short short8;
typedef __attribute__((ext_vector_type(4))) unsigned int u32x4;
typedef __attribute__((ext_vector_type(4))) unsigned short us16x4;

#define D_ 768
#define S_ 1024
#define B_ 2
#define H_ 12
#define G_ 4
#define DH_ 64
#define E_ 8
#define F_ 3072
#define NTOK (B_*S_)   // 2048

// async global->LDS, 16B per lane; dest = wave-uniform base + lane*16
#define GLDS16(g, l) __builtin_amdgcn_global_load_lds( \
    (const __attribute__((address_space(1))) void*)(g), \
    (__attribute__((address_space(3))) void*)(l), 16, 0, 0)

DEV unsigned short f2bf(float f){
  unsigned int b = __float_as_uint(f);
  b += 0x7FFFu + ((b >> 16) & 1u);
  return (unsigned short)(b >> 16);
}
DEV float bf2f(unsigned short h){ return __uint_as_float(((unsigned int)h) << 16); }
DEV unsigned int splitbf_pack(float v){
  unsigned short h = f2bf(v);
  unsigned short l = f2bf(v - bf2f(h));
  return (unsigned int)h | ((unsigned int)l << 16);
}

// swizzled LDS read, 128B rows (BK=64 tiles): chunk = 16B unit 0..7
DEV short8 lds_swz(const unsigned short* base, int row, int chunk){
  return *(const short8*)((const char*)base + row*128 + (((chunk ^ (row & 7)) << 4)));
}
// swizzled LDS read, 64B rows (BK=32 tiles): chunk = 16B unit 0..3
DEV short8 lds_swz32(const unsigned short* base, int row, int chunk){
  return *(const short8*)((const char*)base + row*64 + (((chunk ^ (row & 3)) << 4)));
}

// XCD-aware decode: 4 consecutive m-blocks of one panel land on one XCD.
// grid = nPanels * nM with nM % 4 == 0 (generic in nM).
DEV void swz_decode(int Fb, int nPanels, int& m, int& panel){
  int xcd = Fb & 7;
  int a = Fb >> 3;
  int mi = a & 3;
  int pid = (a >> 2)*8 + xcd;
  m = (pid / nPanels)*4 + mi;
  panel = pid % nPanels;
}

// ---------------- transpose-cast-split (single) ----------------
__global__ __launch_bounds__(256) void tcast_kernel(const float* __restrict__ W,
                                                    unsigned short* __restrict__ Wh,
                                                    unsigned short* __restrict__ Wl,
                                                    int K, int N){
  __shared__ float tile[32][33];
  long long zoff = (long long)blockIdx.z * K * N;
  const float* Wz = W + zoff;
  int n0 = blockIdx.x*32, k0 = blockIdx.y*32;
  int tx = threadIdx.x, ty = threadIdx.y;
  #pragma unroll
  for (int i=0;i<4;i++){
    int r = ty + i*8;
    tile[r][tx] = Wz[(long long)(k0+r)*N + n0 + tx];
  }
  __syncthreads();
  #pragma unroll
  for (int i=0;i<4;i++){
    int r = ty + i*8;
    float v = tile[tx][r];
    unsigned int hl = splitbf_pack(v);
    long long o = zoff + (long long)(n0+r)*K + k0 + tx;
    Wh[o] = (unsigned short)(hl & 0xFFFFu);
    if (Wl) Wl[o] = (unsigned short)(hl >> 16);
  }
}

// ---------------- transpose-cast-split, 4 weights batched over z ----------------
struct TC4 {
  const float* s[4];
  unsigned short* h[4];
  unsigned short* l[4];
};
__global__ __launch_bounds__(256) void tcast4_kernel(TC4 tc, int K, int N){
  __shared__ float tile[32][33];
  int zi = blockIdx.z;
  const float* Wz = tc.s[zi];
  unsigned short* Wh = tc.h[zi];
  unsigned short* Wl = tc.l[zi];
  int n0 = blockIdx.x*32, k0 = blockIdx.y*32;
  int tx = threadIdx.x, ty = threadIdx.y;
  #pragma unroll
  for (int i=0;i<4;i++){
    int r = ty + i*8;
    tile[r][tx] = Wz[(long long)(k0+r)*N + n0 + tx];
  }
  __syncthreads();
  #pragma unroll
  for (int i=0;i<4;i++){
    int r = ty + i*8;
    float v = tile[tx][r];
    unsigned int hl = splitbf_pack(v);
    long long o = (long long)(n0+r)*K + k0 + tx;
    Wh[o] = (unsigned short)(hl & 0xFFFFu);
    Wl[o] = (unsigned short)(hl >> 16);
  }
}

// ---------------- row split (enc only) ----------------
__global__ void split_rows(const float* __restrict__ in, int ld, int width,
                           unsigned short* __restrict__ hi, unsigned short* __restrict__ lo){
  long long t = blockIdx.x;
  int c = threadIdx.x*4;
  f32x4 v = *(const f32x4*)(in + t*ld + c);
  unsigned int p0 = splitbf_pack(v.x), p1 = splitbf_pack(v.y);
  unsigned int p2 = splitbf_pack(v.z), p3 = splitbf_pack(v.w);
  us16x4 h, l;
  h.x=(unsigned short)p0; l.x=(unsigned short)(p0>>16);
  h.y=(unsigned short)p1; l.y=(unsigned short)(p1>>16);
  h.z=(unsigned short)p2; l.z=(unsigned short)(p2>>16);
  h.w=(unsigned short)p3; l.w=(unsigned short)(p3>>16);
  *(us16x4*)(hi + t*width + c) = h;
  *(us16x4*)(lo + t*width + c) = l;
}

// ---------------- bias concat ----------------
__global__ void concat_bias(const float* __restrict__ b0, int n0,
                            const float* __restrict__ b1, int n1,
                            const float* __restrict__ b2, int n2,
                            float* __restrict__ out){
  int i = blockIdx.x*256 + threadIdx.x;
  if (i < n0) out[i] = b0[i];
  else if (i < n0+n1) out[i] = b1[i-n0];
  else if (i < n0+n1+n2) out[i] = b2[i-n0-n1];
}

// ---------------- LayerNorm ----------------
__global__ __launch_bounds__(256) void ln_kernel(const float* __restrict__ x,
                                                 const float* __restrict__ sc,
                                                 const float* __restrict__ bi,
                                                 unsigned short* __restrict__ outh,
                                                 unsigned short* __restrict__ outl,
                                                 float* __restrict__ outf){
  __shared__ float red[8];
  long long row = blockIdx.x;
  const float* xr = x + row*D_;
  int tid = threadIdx.x;
  float v0 = xr[tid], v1 = xr[tid+256], v2 = xr[tid+512];
  float s = v0+v1+v2;
  float q = v0*v0 + v1*v1 + v2*v2;
  #pragma unroll
  for (int off=32; off; off>>=1){ s += __shfl_xor(s, off); q += __shfl_xor(q, off); }
  int lane = tid & 63, w = tid >> 6;
  if (lane == 0){ red[w] = s; red[4+w] = q; }
  __syncthreads();
  s = red[0]+red[1]+red[2]+red[3];
  q = red[4]+red[5]+red[6]+red[7];
  float mu  = s * (1.0f/D_);
  float var = q * (1.0f/D_) - mu*mu;
  float rstd = rsqrtf(var + 1e-6f);
  #pragma unroll
  for (int i=0;i<3;i++){
    int idx = tid + 256*i;
    float vv = (i==0) ? v0 : (i==1) ? v1 : v2;
    float o = (vv - mu)*rstd*sc[idx] + bi[idx];
    unsigned int pk = splitbf_pack(o);
    outh[row*D_ + idx] = (unsigned short)(pk & 0xFFFFu);
    if (outl) outl[row*D_ + idx] = (unsigned short)(pk >> 16);
    if (outf) outf[row*D_ + idx] = o;
  }
}

// ---------------- gemm3: dual-plane split GEMM, BM=64 BN=64 BK=64 ----------------
// grid = nX * 32 m-blocks. mode 0: Cf fp32 (+resid). mode 1: attention epilogue.
__global__ __launch_bounds__(256) void gemm3(
    int nX, int nQ,
    const unsigned short* __restrict__ A0h, const unsigned short* __restrict__ A0l, int lda0,
    const unsigned short* __restrict__ W0h, const unsigned short* __restrict__ W0l,
    const float* __restrict__ bias0,
    const unsigned short* __restrict__ A1h, const unsigned short* __restrict__ A1l, int lda1,
    const unsigned short* __restrict__ W1h, const unsigned short* __restrict__ W1l,
    const float* __restrict__ bias1,
    int K, int mode,
    const float* __restrict__ resid, int ldr,
    float* __restrict__ Cf, int ldc,
    float* __restrict__ qout,
    unsigned short* __restrict__ kh, unsigned short* __restrict__ kl,
    float* __restrict__ vout)
{
  __shared__ __align__(16) unsigned short AshH[64*64];
  __shared__ __align__(16) unsigned short AshL[64*64];
  __shared__ __align__(16) unsigned short BshH[64*64];
  __shared__ __align__(16) unsigned short BshL[64*64];
  int mB, panel;
  swz_decode(blockIdx.x, nX, mB, panel);
  const int r0 = mB*64;
  const int tid = threadIdx.x;
  const int lane = tid & 63;
  const int wv = tid >> 6;
  const int wr = (wv>>1)*32, wc = (wv&1)*32;
  const int l15 = lane & 15, l4 = lane >> 4;
  const int sr = lane >> 3;
  const int sc = (lane & 7) ^ sr;

  const unsigned short *Ah, *Al, *Wh, *Wl;
  int lda, wn0, colbase;
  if (panel < nQ){
    Ah = A0h; Al = A0l; lda = lda0; Wh = W0h; Wl = W0l;
    wn0 = panel*64; colbase = panel*64;
  } else {
    Ah = A1h; Al = A1l; lda = lda1; Wh = W1h; Wl = W1l;
    wn0 = (panel - nQ)*64; colbase = 768 + (panel - nQ)*64;
  }

  f32x4 acc[2][2];
  #pragma unroll
  for (int i=0;i<2;i++)
    #pragma unroll
    for (int j=0;j<2;j++) acc[i][j] = (f32x4){0.f,0.f,0.f,0.f};

  for (int k0 = 0; k0 < K; k0 += 64){
    #pragma unroll
    for (int i=0;i<2;i++){
      int seg = wv*2 + i;
      long long asrc = (long long)(r0 + seg*8 + sr)*lda + k0 + sc*8;
      long long bsrc = (long long)(wn0 + seg*8 + sr)*K + k0 + sc*8;
      GLDS16(Ah + asrc, AshH + seg*8*64);
      GLDS16(Al + asrc, AshL + seg*8*64);
      GLDS16(Wh + bsrc, BshH + seg*8*64);
      GLDS16(Wl + bsrc, BshL + seg*8*64);
    }
    __syncthreads();
    #pragma unroll
    for (int ks=0; ks<2; ks++){
      int chunk = ks*4 + l4;
      short8 bh[2], bl[2];
      #pragma unroll
      for (int fj=0; fj<2; fj++){
        bh[fj] = lds_swz(BshH, wc + fj*16 + l15, chunk);
        bl[fj] = lds_swz(BshL, wc + fj*16 + l15, chunk);
      }
      #pragma unroll
      for (int fi=0; fi<2; fi++){
        short8 ah = lds_swz(AshH, wr + fi*16 + l15, chunk);
        short8 al = lds_swz(AshL, wr + fi*16 + l15, chunk);
        #pragma unroll
        for (int fj=0; fj<2; fj++){
          acc[fi][fj] = __builtin_amdgcn_mfma_f32_16x16x32_bf16(ah, bh[fj], acc[fi][fj], 0,0,0);
          acc[fi][fj] = __builtin_amdgcn_mfma_f32_16x16x32_bf16(al, bh[fj], acc[fi][fj], 0,0,0);
          acc[fi][fj] = __builtin_amdgcn_mfma_f32_16x16x32_bf16(ah, bl[fj], acc[fi][fj], 0,0,0);
        }
      }
    }
    __syncthreads();
  }

  #pragma unroll
  for (int fi=0; fi<2; fi++)
  #pragma unroll
  for (int fj=0; fj<2; fj++)
  #pragma unroll
  for (int reg=0; reg<4; reg++){
    int r = r0 + wr + fi*16 + l4*4 + reg;
    if (mode == 0){
      int col = wn0 + wc + fj*16 + l15;
      float val = acc[fi][fj][reg] + bias0[col];
      if (resid) val += resid[(long long)r*ldr + col];
      Cf[(long long)r*ldc + col] = val;
    } else {
      int lcol = colbase + wc + fj*16 + l15;
      if (lcol < 768){
        float val = acc[fi][fj][reg] + bias0[lcol];
        qout[(long long)r*768 + lcol] = val;
      } else {
        float val = acc[fi][fj][reg] + ((panel < nQ) ? bias0[lcol] : bias1[lcol-768]);
        int c2 = lcol - 768;
        if (c2 < 256){
          unsigned int pk = splitbf_pack(val);
          kh[(long long)r*256 + c2] = (unsigned short)(pk & 0xFFFFu);
          kl[(long long)r*256 + c2] = (unsigned short)(pk >> 16);
        } else {
          vout[(long long)r*256 + (c2 - 256)] = val;
        }
      }
    }
  }
}

// ---------------- MoE expert GEMM: BM=BMP BN=BNP BK=32, dbuf + counted vmcnt ----------------
template<int BMP, int BNP>
__global__ __launch_bounds__(256) void gemm_nt(
    int nX, int nzPerE,
    const unsigned short* __restrict__ A, int lda,
    const unsigned short* __restrict__ Wt, long long wstride,
    const float* __restrict__ bias, int bias_stride,
    const int* __restrict__ counts,
    const int* __restrict__ a_idx, int a_idx_stride,
    float* __restrict__ Cf, long long partStride,
    unsigned short* __restrict__ Cb, int ldc,
    int K, int do_gelu)
{
  constexpr int ASEG = BMP/64;     // A segments per wave per stage
  constexpr int NB = BNP/64;       // B segments per wave per stage
  constexpr int MI = BMP/32;       // per-wave A fragment count
  constexpr int NF = BNP/32;       // per-wave B fragment count
  __shared__ __align__(16) unsigned short As[2][BMP*32];
  __shared__ __align__(16) unsigned short Bs[2][BNP*32];
  int mB, panel;
  swz_decode(blockIdx.x, nX*E_*nzPerE, mB, panel);
  const int n0 = (panel % nX)*BNP;
  const int zI = panel / nX;
  const int z = zI / nzPerE;
  const int kp = zI % nzPerE;
  const int Mz = counts[z];
  const int r0 = mB*BMP;
  if (r0 >= Mz) return;
  int obase = 0;
  for (int e=0;e<z;e++) obase += counts[e];
  const unsigned short* Wz = Wt + (long long)z*wstride;
  const float* bz = bias + (long long)z*bias_stride;
  const int kLen = K / nzPerE;
  const int kBeg = kp * kLen;
  const int tid = threadIdx.x;
  const int lane = tid & 63;
  const int wv = tid >> 6;
  const int wr = (wv>>1)*(BMP/2), wc = (wv&1)*(BNP/2);
  const int l15 = lane & 15, l4 = lane >> 4;
  const int r16 = lane >> 2;
  const int sc4 = (lane & 3) ^ (r16 & 3);

  long long arow[ASEG];
  #pragma unroll
  for (int i=0;i<ASEG;i++){
    int seg = wv*ASEG + i;
    int r = r0 + seg*16 + r16;
    int rcl = (r < Mz) ? r : (Mz-1);
    arow[i] = a_idx ? (long long)a_idx[(long long)z*a_idx_stride + rcl]
                    : (long long)(obase + rcl);
  }

  f32x4 acc[MI][NF];
  #pragma unroll
  for (int i=0;i<MI;i++)
    #pragma unroll
    for (int j=0;j<NF;j++) acc[i][j] = (f32x4){0.f,0.f,0.f,0.f};

  auto stage = [&](int buf, int k0){
    #pragma unroll
    for (int i=0;i<ASEG;i++){
      int seg = wv*ASEG + i;
      GLDS16(A + arow[i]*lda + k0 + sc4*8, &As[buf][seg*512]);
    }
    #pragma unroll
    for (int i=0;i<NB;i++){
      int seg = wv*NB + i;
      GLDS16(Wz + (long long)(n0 + seg*16 + r16)*K + k0 + sc4*8, &Bs[buf][seg*512]);
    }
  };

  const int nsteps = kLen >> 5;
  stage(0, kBeg);
  int cur = 0;
  for (int t=0; t<nsteps; t++){
    if (t+1 < nsteps){
      stage(cur^1, kBeg + (t+1)*32);
      if constexpr (ASEG + NB == 2)      asm volatile("s_waitcnt vmcnt(2)" ::: "memory");
      else if constexpr (ASEG + NB == 3) asm volatile("s_waitcnt vmcnt(3)" ::: "memory");
      else                               asm volatile("s_waitcnt vmcnt(4)" ::: "memory");
    } else {
      asm volatile("s_waitcnt vmcnt(0)" ::: "memory");
    }
    __builtin_amdgcn_s_barrier();
    __builtin_amdgcn_sched_barrier(0);
    {
      short8 a[MI], b[NF];
      #pragma unroll
      for (int f=0; f<MI; f++)
        a[f] = lds_swz32(&As[cur][0], wr + f*16 + l15, l4);
      #pragma unroll
      for (int f=0; f<NF; f++)
        b[f] = lds_swz32(&Bs[cur][0], wc + f*16 + l15, l4);
      #pragma unroll
      for (int fi=0; fi<MI; fi++)
        #pragma unroll
        for (int fj=0; fj<NF; fj++)
          acc[fi][fj] = __builtin_amdgcn_mfma_f32_16x16x32_bf16(a[fi], b[fj], acc[fi][fj], 0,0,0);
    }
    __builtin_amdgcn_s_barrier();
    cur ^= 1;
  }

  #pragma unroll
  for (int fi=0; fi<MI; fi++)
  #pragma unroll
  for (int fj=0; fj<NF; fj++)
  #pragma unroll
  for (int reg=0; reg<4; reg++){
    int r = r0 + wr + fi*16 + l4*4 + reg;
    if (r >= Mz) continue;
    int col = n0 + wc + fj*16 + l15;
    float val = acc[fi][fj][reg] + (kp == 0 ? bz[col] : 0.0f);
    if (do_gelu){
      float xx = val;
      float u = 0.7978845608028654f*(xx + 0.044715f*xx*xx*xx);
      float t = 1.0f - 2.0f/(__expf(2.0f*u) + 1.0f);
      val = 0.5f*xx*(1.0f + t);
    }
    long long orow = (long long)obase + r;
    if (Cf) Cf[kp*partStride + orow*ldc + col] = val;
    if (Cb) Cb[orow*ldc + col] = f2bf(val);
  }
}

// ---------------- transpose-split V: vbuf fp32 [b*1024+s][256] -> vt[(b*4+g)*64+d][1024] ----------------
__global__ __launch_bounds__(256) void vt_split_kernel(const float* __restrict__ vin,
                                                       unsigned short* __restrict__ vth,
                                                       unsigned short* __restrict__ vtl){
  __shared__ float tile[32][33];
  int s0 = blockIdx.x*32, d0 = blockIdx.y*32;
  int bg = blockIdx.z; int b = bg >> 2, g = bg & 3;
  int tx = threadIdx.x, ty = threadIdx.y;
  #pragma unroll
  for (int i=0;i<4;i++){
    int r = ty + i*8;
    tile[r][tx] = vin[(long long)(b*1024 + s0 + r)*256 + g*64 + d0 + tx];
  }
  __syncthreads();
  #pragma unroll
  for (int i=0;i<4;i++){
    int d = d0 + ty + i*8;
    unsigned int pk = splitbf_pack(tile[tx][ty + i*8]);
    long long o = (long long)(bg*64 + d)*1024 + s0 + tx;
    vth[o] = (unsigned short)(pk & 0xFFFFu);
    vtl[o] = (unsigned short)(pk >> 16);
  }
}

// ---------------- MFMA flash attention, split-bf16x3, glds-staged K/V ----------------
#define AT_LDP 76
__global__ __launch_bounds__(256, 2) void attn_mfma(
    const float* __restrict__ q, int qld,
    const unsigned short* __restrict__ kh, const unsigned short* __restrict__ kl,
    const unsigned short* __restrict__ vth, const unsigned short* __restrict__ vtl,
    unsigned short* __restrict__ ctxh, unsigned short* __restrict__ ctxl, int causal)
{
  __shared__ __align__(16) unsigned short KhS[64*64];
  __shared__ __align__(16) unsigned short KlS[64*64];
  __shared__ __align__(16) unsigned short VhS[64*64];
  __shared__ __align__(16) unsigned short VlS[64*64];
  __shared__ __align__(16) unsigned int   Pp[4][16*AT_LDP];

  const int qblk = blockIdx.x;
  const int h = blockIdx.y;
  const int b = blockIdx.z;
  const int g = h / (H_/G_);
  const int tid = threadIdx.x;
  const int lane = tid & 63;
  const int w = tid >> 6;
  const int l15 = lane & 15;
  const int l4 = lane >> 4;
  const int sr = lane >> 3;
  const int sc = (lane & 7) ^ sr;
  const int qb0 = qblk*64;

  short8 qh[2], ql[2];
  #pragma unroll
  for (int ks=0; ks<2; ks++){
    const float* qp = q + ((long long)(b*S_ + qb0 + w*16 + l15))*qld + h*DH_ + ks*32 + l4*8;
    f32x4 q0 = *(const f32x4*)qp;
    f32x4 q1 = *(const f32x4*)(qp + 4);
    float qq[8] = {q0.x,q0.y,q0.z,q0.w,q1.x,q1.y,q1.z,q1.w};
    #pragma unroll
    for (int j=0;j<8;j++){
      unsigned int pk = splitbf_pack(qq[j]*0.125f);
      qh[ks][j] = (short)(pk & 0xFFFFu);
      ql[ks][j] = (short)(pk >> 16);
    }
  }

  f32x4 o[4];
  #pragma unroll
  for (int fd=0; fd<4; fd++) o[fd] = (f32x4){0.f,0.f,0.f,0.f};
  float m[4]    = {-3.0e38f,-3.0e38f,-3.0e38f,-3.0e38f};
  float lsum[4] = {0.f,0.f,0.f,0.f};

  const int ntiles = causal ? (qblk + 1) : (S_/64);
  for (int kt=0; kt<ntiles; kt++){
    __syncthreads();
    #pragma unroll
    for (int i=0;i<2;i++){
      int seg = w*2 + i;
      int row = seg*8 + sr;
      long long ksrc = (long long)(b*S_ + kt*64 + row)*(G_*DH_) + g*DH_ + sc*8;
      long long vsrc = (long long)((b*G_ + g)*64 + row)*S_ + kt*64 + sc*8;
      GLDS16(kh  + ksrc, KhS + seg*8*64);
      GLDS16(kl  + ksrc, KlS + seg*8*64);
      GLDS16(vth + vsrc, VhS + seg*8*64);
      GLDS16(vtl + vsrc, VlS + seg*8*64);
    }
    __syncthreads();

    f32x4 s[4];
    #pragma unroll
    for (int fj=0; fj<4; fj++) s[fj] = (f32x4){0.f,0.f,0.f,0.f};
    #pragma unroll
    for (int ks=0; ks<2; ks++){
      int chunk = ks*4 + l4;
      #pragma unroll
      for (int fj=0; fj<4; fj++){
        short8 bh = lds_swz(KhS, fj*16 + l15, chunk);
        short8 bl = lds_swz(KlS, fj*16 + l15, chunk);
        s[fj] = __builtin_amdgcn_mfma_f32_16x16x32_bf16(qh[ks], bh, s[fj], 0,0,0);
        s[fj] = __builtin_amdgcn_mfma_f32_16x16x32_bf16(ql[ks], bh, s[fj], 0,0,0);
        s[fj] = __builtin_amdgcn_mfma_f32_16x16x32_bf16(qh[ks], bl, s[fj], 0,0,0);
      }
    }

    if (causal && kt == qblk){
      #pragma unroll
      for (int fj=0; fj<4; fj++){
        int key = kt*64 + fj*16 + l15;
        #pragma unroll
        for (int reg=0; reg<4; reg++){
          int qr = qb0 + w*16 + l4*4 + reg;
          if (key > qr) s[fj][reg] = -3.0e38f;
        }
      }
    }

    float c[4], pmax[4];
    #pragma unroll
    for (int reg=0; reg<4; reg++){
      float mx = fmaxf(fmaxf(s[0][reg], s[1][reg]), fmaxf(s[2][reg], s[3][reg]));
      mx = fmaxf(mx, __shfl_xor(mx, 1));
      mx = fmaxf(mx, __shfl_xor(mx, 2));
      mx = fmaxf(mx, __shfl_xor(mx, 4));
      mx = fmaxf(mx, __shfl_xor(mx, 8));
      float mn = fmaxf(m[reg], mx);
      c[reg] = __expf(m[reg] - mn);
      m[reg] = mn;
      pmax[reg] = mn;
    }
    float psum[4] = {0.f,0.f,0.f,0.f};
    #pragma unroll
    for (int fj=0; fj<4; fj++){
      #pragma unroll
      for (int reg=0; reg<4; reg++){
        float pv = __expf(s[fj][reg] - pmax[reg]);
        psum[reg] += pv;
        Pp[w][(l4*4 + reg)*AT_LDP + fj*16 + l15] = splitbf_pack(pv);
      }
    }
    #pragma unroll
    for (int reg=0; reg<4; reg++){
      float ps = psum[reg];
      ps += __shfl_xor(ps, 1); ps += __shfl_xor(ps, 2);
      ps += __shfl_xor(ps, 4); ps += __shfl_xor(ps, 8);
      lsum[reg] = lsum[reg]*c[reg] + ps;
      o[0][reg] *= c[reg]; o[1][reg] *= c[reg];
      o[2][reg] *= c[reg]; o[3][reg] *= c[reg];
    }

    #pragma unroll
    for (int ks=0; ks<2; ks++){
      int chunk = ks*4 + l4;
      u32x4 pa = *(const u32x4*)&Pp[w][l15*AT_LDP + ks*32 + l4*8];
      u32x4 pb = *(const u32x4*)&Pp[w][l15*AT_LDP + ks*32 + l4*8 + 4];
      short8 ph, pl;
      #pragma unroll
      for (int j=0;j<4;j++){
        ph[j]   = (short)(pa[j] & 0xFFFFu); pl[j]   = (short)(pa[j] >> 16);
        ph[4+j] = (short)(pb[j] & 0xFFFFu); pl[4+j] = (short)(pb[j] >> 16);
      }
      #pragma unroll
      for (int fd=0; fd<4; fd++){
        short8 vh = lds_swz(VhS, fd*16 + l15, chunk);
        short8 vl = lds_swz(VlS, fd*16 + l15, chunk);
        o[fd] = __builtin_amdgcn_mfma_f32_16x16x32_bf16(ph, vh, o[fd], 0,0,0);
        o[fd] = __builtin_amdgcn_mfma_f32_16x16x32_bf16(pl, vh, o[fd], 0,0,0);
        o[fd] = __builtin_amdgcn_mfma_f32_16x16x32_bf16(ph, vl, o[fd], 0,0,0);
      }
    }
  }

  #pragma unroll
  for (int reg=0; reg<4; reg++){
    float inv = 1.0f / lsum[reg];
    long long tok = b*S_ + qb0 + w*16 + l4*4 + reg;
    #pragma unroll
    for (int fd=0; fd<4; fd++){
      unsigned int pk = splitbf_pack(o[fd][reg]*inv);
      long long oidx = tok*D_ + h*DH_ + fd*16 + l15;
      ctxh[oidx] = (unsigned short)(pk & 0xFFFFu);
      ctxl[oidx] = (unsigned short)(pk >> 16);
    }
  }
}

// ---------------- MoE gate ----------------
__global__ __launch_bounds__(256) void gate_kernel(const float* __restrict__ xnf,
                                                   const float* __restrict__ gw,
                                                   const float* __restrict__ gb,
                                                   int* __restrict__ counts,
                                                   int* __restrict__ toklist,
                                                   int* __restrict__ route_e,
                                                   int* __restrict__ route_pos,
                                                   float* __restrict__ route_w){
  int t = blockIdx.x*4 + (threadIdx.x >> 6);
  int lane = threadIdx.x & 63;
  float acc[E_];
  #pragma unroll
  for (int e=0;e<E_;e++) acc[e] = 0.f;
  #pragma unroll
  for (int i=0;i<12;i++){
    int d = lane + 64*i;
    float xv = xnf[(long long)t*D_ + d];
    const float* w = gw + (long long)d*E_;
    #pragma unroll
    for (int e=0;e<E_;e++) acc[e] += xv*w[e];
  }
  #pragma unroll
  for (int off=32; off; off>>=1)
    #pragma unroll
    for (int e=0;e<E_;e++) acc[e] += __shfl_xor(acc[e], off);
  if (lane == 0){
    #pragma unroll
    for (int e=0;e<E_;e++) acc[e] += gb[e];
    int e0 = 0;
    #pragma unroll
    for (int e=1;e<E_;e++) if (acc[e] > acc[e0]) e0 = e;
    int e1 = -1;
    #pragma unroll
    for (int e=0;e<E_;e++) if (e != e0 && (e1 < 0 || acc[e] > acc[e1])) e1 = e;
    float w0 = 1.0f/(1.0f + __expf(acc[e1] - acc[e0]));
    float w1 = 1.0f - w0;
    int p0 = atomicAdd(&counts[e0], 1);
    int p1 = atomicAdd(&counts[e1], 1);
    toklist[e0*NTOK + p0] = t;
    toklist[e1*NTOK + p1] = t;
    route_e[2*t]   = e0; route_e[2*t+1]   = e1;
    route_pos[2*t] = p0; route_pos[2*t+1] = p1;
    route_w[2*t]   = w0; route_w[2*t+1]   = w1;
  }
}

__global__ __launch_bounds__(192) void combine_kernel(const float* __restrict__ xb,
                                                      const float* __restrict__ y,
                                                      long long partStride,
                                                      const int* __restrict__ counts,
                                                      const int* __restrict__ route_e,
                                                      const int* __restrict__ route_pos,
                                                      const float* __restrict__ route_w,
                                                      float* __restrict__ out){
  int t = blockIdx.x;
  int i = threadIdx.x;
  int e0 = route_e[2*t], e1 = route_e[2*t+1];
  int off0 = 0, off1 = 0;
  for (int e=0;e<E_;e++){
    if (e < e0) off0 += counts[e];
    if (e < e1) off1 += counts[e];
  }
  long long s0 = off0 + route_pos[2*t];
  long long s1 = off1 + route_pos[2*t+1];
  float w0 = route_w[2*t], w1 = route_w[2*t+1];
  f32x4 xv = *(const f32x4*)(xb + (long long)t*D_ + i*4);
  f32x4 y0 = (f32x4){0.f,0.f,0.f,0.f};
  f32x4 y1 = (f32x4){0.f,0.f,0.f,0.f};
  #pragma unroll
  for (int kp=0; kp<2; kp++){
    y0 += *(const f32x4*)(y + kp*partStride + s0*D_ + i*4);
    y1 += *(const f32x4*)(y + kp*partStride + s1*D_ + i*4);
  }
  f32x4 o = xv + w0*y0 + w1*y1;
  *(f32x4*)(out + (long long)t*D_ + i*4) = o;
}

// ---------------- host orchestration ----------------
extern "C" void kernel_launch(void* const* d_in, const int* in_sizes, int n_in,
                              void* d_out, int out_size, void* d_ws, size_t ws_size,
                              hipStream_t stream) {
  (void)in_sizes; (void)n_in; (void)out_size; (void)ws_size;
  const float* x     = (const float*)d_in[0];
  const float* enc   = (const float*)d_in[1];
  const float* ln1s  = (const float*)d_in[2];
  const float* ln1b  = (const float*)d_in[3];
  const float* ln2s  = (const float*)d_in[4];
  const float* ln2b  = (const float*)d_in[5];
  const float* ln3s  = (const float*)d_in[6];
  const float* ln3b  = (const float*)d_in[7];
  const float* sa_wq = (const float*)d_in[8];
  const float* sa_bq = (const float*)d_in[9];
  const float* sa_wk = (const float*)d_in[10];
  const float* sa_bk = (const float*)d_in[11];
  const float* sa_wv = (const float*)d_in[12];
  const float* sa_bv = (const float*)d_in[13];
  const float* sa_wo = (const float*)d_in[14];
  const float* sa_bo = (const float*)d_in[15];
  const float* ca_wq = (const float*)d_in[16];
  const float* ca_bq = (const float*)d_in[17];
  const float* ca_wk = (const float*)d_in[18];
  const float* ca_bk = (const float*)d_in[19];
  const float* ca_wv = (const float*)d_in[20];
  const float* ca_bv = (const float*)d_in[21];
  const float* ca_wo = (const float*)d_in[22];
  const float* ca_bo = (const float*)d_in[23];
  const float* gate_w= (const float*)d_in[24];
  const float* gate_b= (const float*)d_in[25];
  const float* w1    = (const float*)d_in[26];
  const float* b1    = (const float*)d_in[27];
  const float* w2    = (const float*)d_in[28];
  const float* b2    = (const float*)d_in[29];
  float* out = (float*)d_out;

  char* p = (char*)d_ws;
  auto alloc = [&](size_t bytes)->void*{
    void* r = (void*)p;
    p += (bytes + 255) & ~(size_t)255;
    return r;
  };
  unsigned short* wqkvh_sa = (unsigned short*)alloc((size_t)1280*768*2);
  unsigned short* wqkvl_sa = (unsigned short*)alloc((size_t)1280*768*2);
  unsigned short* woh_sa   = (unsigned short*)alloc((size_t)768*768*2);
  unsigned short* wol_sa   = (unsigned short*)alloc((size_t)768*768*2);
  unsigned short* wqh_ca   = (unsigned short*)alloc((size_t)768*768*2);
  unsigned short* wql_ca   = (unsigned short*)alloc((size_t)768*768*2);
  unsigned short* wkvh_ca  = (unsigned short*)alloc((size_t)512*768*2);
  unsigned short* wkvl_ca  = (unsigned short*)alloc((size_t)512*768*2);
  unsigned short* woh_ca   = (unsigned short*)alloc((size_t)768*768*2);
  unsigned short* wol_ca   = (unsigned short*)alloc((size_t)768*768*2);
  unsigned short* w1T = (unsigned short*)alloc((size_t)E_*D_*F_*2);
  unsigned short* w2T = (unsigned short*)alloc((size_t)E_*D_*F_*2);
  float* bqkv_sa = (float*)alloc(1280*4);
  float* bkv_ca  = (float*)alloc(512*4);
  unsigned short* ench = (unsigned short*)alloc((size_t)NTOK*D_*2);
  unsigned short* encl = (unsigned short*)alloc((size_t)NTOK*D_*2);
  unsigned short* xh   = (unsigned short*)alloc((size_t)NTOK*D_*2);
  unsigned short* xl   = (unsigned short*)alloc((size_t)NTOK*D_*2);
  unsigned short* ctxh = (unsigned short*)alloc((size_t)NTOK*D_*2);
  unsigned short* ctxl = (unsigned short*)alloc((size_t)NTOK*D_*2);
  unsigned short* xn_b = (unsigned short*)alloc((size_t)NTOK*D_*2);
  unsigned short* hbuf = (unsigned short*)alloc((size_t)2*NTOK*F_*2);
  unsigned short* khp   = (unsigned short*)alloc((size_t)NTOK*G_*DH_*2);
  unsigned short* klp   = (unsigned short*)alloc((size_t)NTOK*G_*DH_*2);
  unsigned short* vtp_h = (unsigned short*)alloc((size_t)NTOK*G_*DH_*2);
  unsigned short* vtp_l = (unsigned short*)alloc((size_t)NTOK*G_*DH_*2);
  float* vbuf = (float*)alloc((size_t)NTOK*G_*DH_*4);
  float* qbuf = (float*)alloc((size_t)NTOK*D_*4);
  float* xnf  = (float*)alloc((size_t)NTOK*D_*4);
  float* xbuf = (float*)alloc((size_t)NTOK*D_*4);
  float* ybuf = (float*)alloc((size_t)4*NTOK*D_*4);
  int* counts    = (int*)alloc(E_*4);
  int* toklist   = (int*)alloc((size_t)E_*NTOK*4);
  int* route_e   = (int*)alloc((size_t)2*NTOK*4);
  int* route_pos = (int*)alloc((size_t)2*NTOK*4);
  float* route_w = (float*)alloc((size_t)2*NTOK*4);

  (void)hipMemsetAsync(counts, 0, E_*sizeof(int), stream);

  dim3 tb(32,8);
  {
    TC4 a;
    a.s[0]=sa_wq; a.h[0]=wqkvh_sa;           a.l[0]=wqkvl_sa;
    a.s[1]=sa_wo; a.h[1]=woh_sa;             a.l[1]=wol_sa;
    a.s[2]=ca_wq; a.h[2]=wqh_ca;             a.l[2]=wql_ca;
    a.s[3]=ca_wo; a.h[3]=woh_ca;             a.l[3]=wol_ca;
    tcast4_kernel<<<dim3(24,24,4), tb, 0, stream>>>(a, 768, 768);
    TC4 b;
    b.s[0]=sa_wk; b.h[0]=wqkvh_sa + 768*768;  b.l[0]=wqkvl_sa + 768*768;
    b.s[1]=sa_wv; b.h[1]=wqkvh_sa + 1024*768; b.l[1]=wqkvl_sa + 1024*768;
    b.s[2]=ca_wk; b.h[2]=wkvh_ca;             b.l[2]=wkvl_ca;
    b.s[3]=ca_wv; b.h[3]=wkvh_ca + 256*768;   b.l[3]=wkvl_ca + 256*768;
    tcast4_kernel<<<dim3(8,24,4), tb, 0, stream>>>(b, 768, 256);
  }
  tcast_kernel<<<dim3(96,24,E_), tb, 0, stream>>>(w1, w1T, nullptr, 768, 3072);
  tcast_kernel<<<dim3(24,96,E_), tb, 0, stream>>>(w2, w2T, nullptr, 3072, 768);
  concat_bias<<<5, 256, 0, stream>>>(sa_bq, 768, sa_bk, 256, sa_bv, 256, bqkv_sa);
  concat_bias<<<2, 256, 0, stream>>>(ca_bk, 256, ca_bv, 256, nullptr, 0, bkv_ca);
  split_rows<<<NTOK, 192, 0, stream>>>(enc, 768, 768, ench, encl);

  // ---- self-attention ----
  ln_kernel<<<NTOK, 256, 0, stream>>>(x, ln1s, ln1b, xh, xl, nullptr);
  gemm3<<<20*32, 256, 0, stream>>>(20, 20,
      xh, xl, 768, wqkvh_sa, wqkvl_sa, bqkv_sa,
      nullptr, nullptr, 0, nullptr, nullptr, nullptr,
      768, 1, nullptr, 0, nullptr, 0,
      qbuf, khp, klp, vbuf);
  vt_split_kernel<<<dim3(32,2,8), tb, 0, stream>>>(vbuf, vtp_h, vtp_l);
  attn_mfma<<<dim3(16,12,2), 256, 0, stream>>>(qbuf, 768, khp, klp, vtp_h, vtp_l, ctxh, ctxl, 1);
  gemm3<<<12*32, 256, 0, stream>>>(12, 12,
      ctxh, ctxl, 768, woh_sa, wol_sa, sa_bo,
      nullptr, nullptr, 0, nullptr, nullptr, nullptr,
      768, 0, x, 768, xbuf, 768,
      nullptr, nullptr, nullptr, nullptr);

  // ---- cross-attention ----
  ln_kernel<<<NTOK, 256, 0, stream>>>(xbuf, ln2s, ln2b, xh, xl, nullptr);
  gemm3<<<20*32, 256, 0, stream>>>(20, 12,
      xh, xl, 768, wqh_ca, wql_ca, ca_bq,
      ench, encl, 768, wkvh_ca, wkvl_ca, bkv_ca,
      768, 1, nullptr, 0, nullptr, 0,
      qbuf, khp, klp, vbuf);
  vt_split_kernel<<<dim3(32,2,8), tb, 0, stream>>>(vbuf, vtp_h, vtp_l);
  attn_mfma<<<dim3(16,12,2), 256, 0, stream>>>(qbuf, 768, khp, klp, vtp_h, vtp_l, ctxh, ctxl, 0);
  gemm3<<<12*32, 256, 0, stream>>>(12, 12,
      ctxh, ctxl, 768, woh_ca, wol_ca, ca_bo,
      nullptr, nullptr, 0, nullptr, nullptr, nullptr,
      768, 0, xbuf, 768, xbuf, 768,
      nullptr, nullptr, nullptr, nullptr);

  // ---- MoE ----
  ln_kernel<<<NTOK, 256, 0, stream>>>(xbuf, ln3s, ln3b, xn_b, nullptr, xnf);
  gate_kernel<<<NTOK/4, 256, 0, stream>>>(xnf, gate_w, gate_b,
      counts, toklist, route_e, route_pos, route_w);
  // w1: BM=64 BN=64, 48 panels x 20 m-blocks (capacity 1280 rows/expert)
  gemm_nt<64,64><<<48*20*E_, 256, 0, stream>>>(48, 1, xn_b, 768, w1T, (long long)F_*D_, b1, F_,
      counts, toklist, NTOK, nullptr, 0, hbuf, F_, 768, 1);
  // w2: BM=64 BN=64, 12 panels x 20 m-blocks, split-K x2
  long long partStride = (long long)2*NTOK*D_;
  gemm_nt<64,64><<<12*20*E_*2, 256, 0, stream>>>(12, 2, hbuf, F_, w2T, (long long)F_*D_, b2, D_,
      counts, nullptr, 0, ybuf, partStride, nullptr, 768, F_, 0);
  combine_kernel<<<NTOK, 192, 0, stream>>>(xbuf, ybuf, partStride,
      counts, route_e, route_pos, route_w, out);
}

// Round 19
// 456.194 us; speedup vs baseline: 1.0334x; 1.0334x over previous
//
#include <hip/hip_runtime.h>

#define DEV __device__ __forceinline__

typedef __attribute__((ext_vector_type(4))) float f32x4;
typedef __attribute__((ext_vector_type(8))) short short8;
typedef __attribute__((ext_vector_type(4))) unsigned int u32x4;
typedef __attribute__((ext_vector_type(4))) unsigned short us16x4;

#define D_ 768
#define S_ 1024
#define B_ 2
#define H_ 12
#define G_ 4
#define DH_ 64
#define E_ 8
#define F_ 3072
#define NTOK (B_*S_)   // 2048

// async global->LDS, 16B per lane; dest = wave-uniform base + lane*16
#define GLDS16(g, l) __builtin_amdgcn_global_load_lds( \
    (const __attribute__((address_space(1))) void*)(g), \
    (__attribute__((address_space(3))) void*)(l), 16, 0, 0)

DEV unsigned short f2bf(float f){
  unsigned int b = __float_as_uint(f);
  b += 0x7FFFu + ((b >> 16) & 1u);
  return (unsigned short)(b >> 16);
}
DEV float bf2f(unsigned short h){ return __uint_as_float(((unsigned int)h) << 16); }
DEV unsigned int splitbf_pack(float v){
  unsigned short h = f2bf(v);
  unsigned short l = f2bf(v - bf2f(h));
  return (unsigned int)h | ((unsigned int)l << 16);
}

// swizzled LDS read, 128B rows (BK=64 tiles): chunk = 16B unit 0..7
DEV short8 lds_swz(const unsigned short* base, int row, int chunk){
  return *(const short8*)((const char*)base + row*128 + (((chunk ^ (row & 7)) << 4)));
}
// swizzled LDS read, 64B rows (BK=32 tiles): chunk = 16B unit 0..3
DEV short8 lds_swz32(const unsigned short* base, int row, int chunk){
  return *(const short8*)((const char*)base + row*64 + (((chunk ^ (row & 3)) << 4)));
}

// XCD-aware decode: 4 consecutive m-blocks of one panel land on one XCD.
DEV void swz_decode(int Fb, int nPanels, int& m, int& panel){
  int xcd = Fb & 7;
  int a = Fb >> 3;
  int mi = a & 3;
  int pid = (a >> 2)*8 + xcd;
  m = (pid / nPanels)*4 + mi;
  panel = pid % nPanels;
}

// ---------------- transpose-cast-split (single) ----------------
__global__ __launch_bounds__(256) void tcast_kernel(const float* __restrict__ W,
                                                    unsigned short* __restrict__ Wh,
                                                    unsigned short* __restrict__ Wl,
                                                    int K, int N){
  __shared__ float tile[32][33];
  long long zoff = (long long)blockIdx.z * K * N;
  const float* Wz = W + zoff;
  int n0 = blockIdx.x*32, k0 = blockIdx.y*32;
  int tx = threadIdx.x, ty = threadIdx.y;
  #pragma unroll
  for (int i=0;i<4;i++){
    int r = ty + i*8;
    tile[r][tx] = Wz[(long long)(k0+r)*N + n0 + tx];
  }
  __syncthreads();
  #pragma unroll
  for (int i=0;i<4;i++){
    int r = ty + i*8;
    float v = tile[tx][r];
    unsigned int hl = splitbf_pack(v);
    long long o = zoff + (long long)(n0+r)*K + k0 + tx;
    Wh[o] = (unsigned short)(hl & 0xFFFFu);
    if (Wl) Wl[o] = (unsigned short)(hl >> 16);
  }
}

// ---------------- transpose-cast-split, 4 weights batched over z ----------------
struct TC4 {
  const float* s[4];
  unsigned short* h[4];
  unsigned short* l[4];
};
__global__ __launch_bounds__(256) void tcast4_kernel(TC4 tc, int K, int N){
  __shared__ float tile[32][33];
  int zi = blockIdx.z;
  const float* Wz = tc.s[zi];
  unsigned short* Wh = tc.h[zi];
  unsigned short* Wl = tc.l[zi];
  int n0 = blockIdx.x*32, k0 = blockIdx.y*32;
  int tx = threadIdx.x, ty = threadIdx.y;
  #pragma unroll
  for (int i=0;i<4;i++){
    int r = ty + i*8;
    tile[r][tx] = Wz[(long long)(k0+r)*N + n0 + tx];
  }
  __syncthreads();
  #pragma unroll
  for (int i=0;i<4;i++){
    int r = ty + i*8;
    float v = tile[tx][r];
    unsigned int hl = splitbf_pack(v);
    long long o = (long long)(n0+r)*K + k0 + tx;
    Wh[o] = (unsigned short)(hl & 0xFFFFu);
    Wl[o] = (unsigned short)(hl >> 16);
  }
}

// ---------------- row split (enc only) ----------------
__global__ void split_rows(const float* __restrict__ in, int ld, int width,
                           unsigned short* __restrict__ hi, unsigned short* __restrict__ lo){
  long long t = blockIdx.x;
  int c = threadIdx.x*4;
  f32x4 v = *(const f32x4*)(in + t*ld + c);
  unsigned int p0 = splitbf_pack(v.x), p1 = splitbf_pack(v.y);
  unsigned int p2 = splitbf_pack(v.z), p3 = splitbf_pack(v.w);
  us16x4 h, l;
  h.x=(unsigned short)p0; l.x=(unsigned short)(p0>>16);
  h.y=(unsigned short)p1; l.y=(unsigned short)(p1>>16);
  h.z=(unsigned short)p2; l.z=(unsigned short)(p2>>16);
  h.w=(unsigned short)p3; l.w=(unsigned short)(p3>>16);
  *(us16x4*)(hi + t*width + c) = h;
  *(us16x4*)(lo + t*width + c) = l;
}

// ---------------- bias concat ----------------
__global__ void concat_bias(const float* __restrict__ b0, int n0,
                            const float* __restrict__ b1, int n1,
                            const float* __restrict__ b2, int n2,
                            float* __restrict__ out){
  int i = blockIdx.x*256 + threadIdx.x;
  if (i < n0) out[i] = b0[i];
  else if (i < n0+n1) out[i] = b1[i-n0];
  else if (i < n0+n1+n2) out[i] = b2[i-n0-n1];
}

// ---------------- LayerNorm ----------------
__global__ __launch_bounds__(256) void ln_kernel(const float* __restrict__ x,
                                                 const float* __restrict__ sc,
                                                 const float* __restrict__ bi,
                                                 unsigned short* __restrict__ outh,
                                                 unsigned short* __restrict__ outl,
                                                 float* __restrict__ outf){
  __shared__ float red[8];
  long long row = blockIdx.x;
  const float* xr = x + row*D_;
  int tid = threadIdx.x;
  float v0 = xr[tid], v1 = xr[tid+256], v2 = xr[tid+512];
  float s = v0+v1+v2;
  float q = v0*v0 + v1*v1 + v2*v2;
  #pragma unroll
  for (int off=32; off; off>>=1){ s += __shfl_xor(s, off); q += __shfl_xor(q, off); }
  int lane = tid & 63, w = tid >> 6;
  if (lane == 0){ red[w] = s; red[4+w] = q; }
  __syncthreads();
  s = red[0]+red[1]+red[2]+red[3];
  q = red[4]+red[5]+red[6]+red[7];
  float mu  = s * (1.0f/D_);
  float var = q * (1.0f/D_) - mu*mu;
  float rstd = rsqrtf(var + 1e-6f);
  #pragma unroll
  for (int i=0;i<3;i++){
    int idx = tid + 256*i;
    float vv = (i==0) ? v0 : (i==1) ? v1 : v2;
    float o = (vv - mu)*rstd*sc[idx] + bi[idx];
    unsigned int pk = splitbf_pack(o);
    outh[row*D_ + idx] = (unsigned short)(pk & 0xFFFFu);
    if (outl) outl[row*D_ + idx] = (unsigned short)(pk >> 16);
    if (outf) outf[row*D_ + idx] = o;
  }
}

// ---------------- gemm3: dual-plane split GEMM, BM=64 BN=64 BK=64 ----------------
__global__ __launch_bounds__(256) void gemm3(
    int nX, int nQ,
    const unsigned short* __restrict__ A0h, const unsigned short* __restrict__ A0l, int lda0,
    const unsigned short* __restrict__ W0h, const unsigned short* __restrict__ W0l,
    const float* __restrict__ bias0,
    const unsigned short* __restrict__ A1h, const unsigned short* __restrict__ A1l, int lda1,
    const unsigned short* __restrict__ W1h, const unsigned short* __restrict__ W1l,
    const float* __restrict__ bias1,
    int K, int mode,
    const float* __restrict__ resid, int ldr,
    float* __restrict__ Cf, int ldc,
    float* __restrict__ qout,
    unsigned short* __restrict__ kh, unsigned short* __restrict__ kl,
    float* __restrict__ vout)
{
  __shared__ __align__(16) unsigned short AshH[64*64];
  __shared__ __align__(16) unsigned short AshL[64*64];
  __shared__ __align__(16) unsigned short BshH[64*64];
  __shared__ __align__(16) unsigned short BshL[64*64];
  int mB, panel;
  swz_decode(blockIdx.x, nX, mB, panel);
  const int r0 = mB*64;
  const int tid = threadIdx.x;
  const int lane = tid & 63;
  const int wv = tid >> 6;
  const int wr = (wv>>1)*32, wc = (wv&1)*32;
  const int l15 = lane & 15, l4 = lane >> 4;
  const int sr = lane >> 3;
  const int sc = (lane & 7) ^ sr;

  const unsigned short *Ah, *Al, *Wh, *Wl;
  int lda, wn0, colbase;
  if (panel < nQ){
    Ah = A0h; Al = A0l; lda = lda0; Wh = W0h; Wl = W0l;
    wn0 = panel*64; colbase = panel*64;
  } else {
    Ah = A1h; Al = A1l; lda = lda1; Wh = W1h; Wl = W1l;
    wn0 = (panel - nQ)*64; colbase = 768 + (panel - nQ)*64;
  }

  f32x4 acc[2][2];
  #pragma unroll
  for (int i=0;i<2;i++)
    #pragma unroll
    for (int j=0;j<2;j++) acc[i][j] = (f32x4){0.f,0.f,0.f,0.f};

  for (int k0 = 0; k0 < K; k0 += 64){
    #pragma unroll
    for (int i=0;i<2;i++){
      int seg = wv*2 + i;
      long long asrc = (long long)(r0 + seg*8 + sr)*lda + k0 + sc*8;
      long long bsrc = (long long)(wn0 + seg*8 + sr)*K + k0 + sc*8;
      GLDS16(Ah + asrc, AshH + seg*8*64);
      GLDS16(Al + asrc, AshL + seg*8*64);
      GLDS16(Wh + bsrc, BshH + seg*8*64);
      GLDS16(Wl + bsrc, BshL + seg*8*64);
    }
    __syncthreads();
    #pragma unroll
    for (int ks=0; ks<2; ks++){
      int chunk = ks*4 + l4;
      short8 bh[2], bl[2];
      #pragma unroll
      for (int fj=0; fj<2; fj++){
        bh[fj] = lds_swz(BshH, wc + fj*16 + l15, chunk);
        bl[fj] = lds_swz(BshL, wc + fj*16 + l15, chunk);
      }
      #pragma unroll
      for (int fi=0; fi<2; fi++){
        short8 ah = lds_swz(AshH, wr + fi*16 + l15, chunk);
        short8 al = lds_swz(AshL, wr + fi*16 + l15, chunk);
        #pragma unroll
        for (int fj=0; fj<2; fj++){
          acc[fi][fj] = __builtin_amdgcn_mfma_f32_16x16x32_bf16(ah, bh[fj], acc[fi][fj], 0,0,0);
          acc[fi][fj] = __builtin_amdgcn_mfma_f32_16x16x32_bf16(al, bh[fj], acc[fi][fj], 0,0,0);
          acc[fi][fj] = __builtin_amdgcn_mfma_f32_16x16x32_bf16(ah, bl[fj], acc[fi][fj], 0,0,0);
        }
      }
    }
    __syncthreads();
  }

  #pragma unroll
  for (int fi=0; fi<2; fi++)
  #pragma unroll
  for (int fj=0; fj<2; fj++)
  #pragma unroll
  for (int reg=0; reg<4; reg++){
    int r = r0 + wr + fi*16 + l4*4 + reg;
    if (mode == 0){
      int col = wn0 + wc + fj*16 + l15;
      float val = acc[fi][fj][reg] + bias0[col];
      if (resid) val += resid[(long long)r*ldr + col];
      Cf[(long long)r*ldc + col] = val;
    } else {
      int lcol = colbase + wc + fj*16 + l15;
      if (lcol < 768){
        float val = acc[fi][fj][reg] + bias0[lcol];
        qout[(long long)r*768 + lcol] = val;
      } else {
        float val = acc[fi][fj][reg] + ((panel < nQ) ? bias0[lcol] : bias1[lcol-768]);
        int c2 = lcol - 768;
        if (c2 < 256){
          unsigned int pk = splitbf_pack(val);
          kh[(long long)r*256 + c2] = (unsigned short)(pk & 0xFFFFu);
          kl[(long long)r*256 + c2] = (unsigned short)(pk >> 16);
        } else {
          vout[(long long)r*256 + (c2 - 256)] = val;
        }
      }
    }
  }
}

// ---------------- MoE expert GEMM: BM=BMP BN=BNP BK=32, dbuf + counted vmcnt ----------------
// Buffer-recycle barrier is a full __syncthreads() (compiler memory fence) to make
// write-after-read across the double buffer provably ordered; the entry barrier keeps
// the counted-vmcnt overlap (prefetch issued before the wait covers the compute phase).
template<int BMP, int BNP>
__global__ __launch_bounds__(256) void gemm_nt(
    int nX, int nzPerE,
    const unsigned short* __restrict__ A, int lda,
    const unsigned short* __restrict__ Wt, long long wstride,
    const float* __restrict__ bias, int bias_stride,
    const int* __restrict__ counts,
    const int* __restrict__ a_idx, int a_idx_stride,
    float* __restrict__ Cf, long long partStride,
    unsigned short* __restrict__ Cb, int ldc,
    int K, int do_gelu)
{
  constexpr int ASEG = BMP/64;
  constexpr int NB = BNP/64;
  constexpr int MI = BMP/32;
  constexpr int NF = BNP/32;
  __shared__ __align__(16) unsigned short As[2][BMP*32];
  __shared__ __align__(16) unsigned short Bs[2][BNP*32];
  int mB, panel;
  swz_decode(blockIdx.x, nX*E_*nzPerE, mB, panel);
  const int n0 = (panel % nX)*BNP;
  const int zI = panel / nX;
  const int z = zI / nzPerE;
  const int kp = zI % nzPerE;
  const int Mz = counts[z];
  const int r0 = mB*BMP;
  if (r0 >= Mz) return;
  int obase = 0;
  for (int e=0;e<z;e++) obase += counts[e];
  const unsigned short* Wz = Wt + (long long)z*wstride;
  const float* bz = bias + (long long)z*bias_stride;
  const int kLen = K / nzPerE;
  const int kBeg = kp * kLen;
  const int tid = threadIdx.x;
  const int lane = tid & 63;
  const int wv = tid >> 6;
  const int wr = (wv>>1)*(BMP/2), wc = (wv&1)*(BNP/2);
  const int l15 = lane & 15, l4 = lane >> 4;
  const int r16 = lane >> 2;
  const int sc4 = (lane & 3) ^ (r16 & 3);

  long long arow[ASEG];
  #pragma unroll
  for (int i=0;i<ASEG;i++){
    int seg = wv*ASEG + i;
    int r = r0 + seg*16 + r16;
    int rcl = (r < Mz) ? r : (Mz-1);
    arow[i] = a_idx ? (long long)a_idx[(long long)z*a_idx_stride + rcl]
                    : (long long)(obase + rcl);
  }

  f32x4 acc[MI][NF];
  #pragma unroll
  for (int i=0;i<MI;i++)
    #pragma unroll
    for (int j=0;j<NF;j++) acc[i][j] = (f32x4){0.f,0.f,0.f,0.f};

  auto stage = [&](int buf, int k0){
    #pragma unroll
    for (int i=0;i<ASEG;i++){
      int seg = wv*ASEG + i;
      GLDS16(A + arow[i]*lda + k0 + sc4*8, &As[buf][seg*512]);
    }
    #pragma unroll
    for (int i=0;i<NB;i++){
      int seg = wv*NB + i;
      GLDS16(Wz + (long long)(n0 + seg*16 + r16)*K + k0 + sc4*8, &Bs[buf][seg*512]);
    }
  };

  const int nsteps = kLen >> 5;
  stage(0, kBeg);
  int cur = 0;
  for (int t=0; t<nsteps; t++){
    if (t+1 < nsteps){
      stage(cur^1, kBeg + (t+1)*32);
      if constexpr (ASEG + NB == 2)      asm volatile("s_waitcnt vmcnt(2)" ::: "memory");
      else if constexpr (ASEG + NB == 3) asm volatile("s_waitcnt vmcnt(3)" ::: "memory");
      else                               asm volatile("s_waitcnt vmcnt(4)" ::: "memory");
    } else {
      asm volatile("s_waitcnt vmcnt(0)" ::: "memory");
    }
    __builtin_amdgcn_s_barrier();          // all waves' tile-t loads landed
    __builtin_amdgcn_sched_barrier(0);     // no LDS-read hoist above this point
    {
      short8 a[MI], b[NF];
      #pragma unroll
      for (int f=0; f<MI; f++)
        a[f] = lds_swz32(&As[cur][0], wr + f*16 + l15, l4);
      #pragma unroll
      for (int f=0; f<NF; f++)
        b[f] = lds_swz32(&Bs[cur][0], wc + f*16 + l15, l4);
      #pragma unroll
      for (int fi=0; fi<MI; fi++)
        #pragma unroll
        for (int fj=0; fj<NF; fj++)
          acc[fi][fj] = __builtin_amdgcn_mfma_f32_16x16x32_bf16(a[fi], b[fj], acc[fi][fj], 0,0,0);
    }
    __syncthreads();                       // full fence: reads of buf[cur] done before reuse
    cur ^= 1;
  }

  #pragma unroll
  for (int fi=0; fi<MI; fi++)
  #pragma unroll
  for (int fj=0; fj<NF; fj++)
  #pragma unroll
  for (int reg=0; reg<4; reg++){
    int r = r0 + wr + fi*16 + l4*4 + reg;
    if (r >= Mz) continue;
    int col = n0 + wc + fj*16 + l15;
    float val = acc[fi][fj][reg] + (kp == 0 ? bz[col] : 0.0f);
    if (do_gelu){
      float xx = val;
      float u = 0.7978845608028654f*(xx + 0.044715f*xx*xx*xx);
      float t = 1.0f - 2.0f/(__expf(2.0f*u) + 1.0f);
      val = 0.5f*xx*(1.0f + t);
    }
    long long orow = (long long)obase + r;
    if (Cf) Cf[kp*partStride + orow*ldc + col] = val;
    if (Cb) Cb[orow*ldc + col] = f2bf(val);
  }
}

// ---------------- transpose-split V: vbuf fp32 [b*1024+s][256] -> vt[(b*4+g)*64+d][1024] ----------------
__global__ __launch_bounds__(256) void vt_split_kernel(const float* __restrict__ vin,
                                                       unsigned short* __restrict__ vth,
                                                       unsigned short* __restrict__ vtl){
  __shared__ float tile[32][33];
  int s0 = blockIdx.x*32, d0 = blockIdx.y*32;
  int bg = blockIdx.z; int b = bg >> 2, g = bg & 3;
  int tx = threadIdx.x, ty = threadIdx.y;
  #pragma unroll
  for (int i=0;i<4;i++){
    int r = ty + i*8;
    tile[r][tx] = vin[(long long)(b*1024 + s0 + r)*256 + g*64 + d0 + tx];
  }
  __syncthreads();
  #pragma unroll
  for (int i=0;i<4;i++){
    int d = d0 + ty + i*8;
    unsigned int pk = splitbf_pack(tile[tx][ty + i*8]);
    long long o = (long long)(bg*64 + d)*1024 + s0 + tx;
    vth[o] = (unsigned short)(pk & 0xFFFFu);
    vtl[o] = (unsigned short)(pk >> 16);
  }
}

// ---------------- MFMA flash attention, split-bf16x3, glds-staged K/V ----------------
#define AT_LDP 76
__global__ __launch_bounds__(256, 2) void attn_mfma(
    const float* __restrict__ q, int qld,
    const unsigned short* __restrict__ kh, const unsigned short* __restrict__ kl,
    const unsigned short* __restrict__ vth, const unsigned short* __restrict__ vtl,
    unsigned short* __restrict__ ctxh, unsigned short* __restrict__ ctxl, int causal)
{
  __shared__ __align__(16) unsigned short KhS[64*64];
  __shared__ __align__(16) unsigned short KlS[64*64];
  __shared__ __align__(16) unsigned short VhS[64*64];
  __shared__ __align__(16) unsigned short VlS[64*64];
  __shared__ __align__(16) unsigned int   Pp[4][16*AT_LDP];

  const int qblk = blockIdx.x;
  const int h = blockIdx.y;
  const int b = blockIdx.z;
  const int g = h / (H_/G_);
  const int tid = threadIdx.x;
  const int lane = tid & 63;
  const int w = tid >> 6;
  const int l15 = lane & 15;
  const int l4 = lane >> 4;
  const int sr = lane >> 3;
  const int sc = (lane & 7) ^ sr;
  const int qb0 = qblk*64;

  short8 qh[2], ql[2];
  #pragma unroll
  for (int ks=0; ks<2; ks++){
    const float* qp = q + ((long long)(b*S_ + qb0 + w*16 + l15))*qld + h*DH_ + ks*32 + l4*8;
    f32x4 q0 = *(const f32x4*)qp;
    f32x4 q1 = *(const f32x4*)(qp + 4);
    float qq[8] = {q0.x,q0.y,q0.z,q0.w,q1.x,q1.y,q1.z,q1.w};
    #pragma unroll
    for (int j=0;j<8;j++){
      unsigned int pk = splitbf_pack(qq[j]*0.125f);
      qh[ks][j] = (short)(pk & 0xFFFFu);
      ql[ks][j] = (short)(pk >> 16);
    }
  }

  f32x4 o[4];
  #pragma unroll
  for (int fd=0; fd<4; fd++) o[fd] = (f32x4){0.f,0.f,0.f,0.f};
  float m[4]    = {-3.0e38f,-3.0e38f,-3.0e38f,-3.0e38f};
  float lsum[4] = {0.f,0.f,0.f,0.f};

  const int ntiles = causal ? (qblk + 1) : (S_/64);
  for (int kt=0; kt<ntiles; kt++){
    __syncthreads();
    #pragma unroll
    for (int i=0;i<2;i++){
      int seg = w*2 + i;
      int row = seg*8 + sr;
      long long ksrc = (long long)(b*S_ + kt*64 + row)*(G_*DH_) + g*DH_ + sc*8;
      long long vsrc = (long long)((b*G_ + g)*64 + row)*S_ + kt*64 + sc*8;
      GLDS16(kh  + ksrc, KhS + seg*8*64);
      GLDS16(kl  + ksrc, KlS + seg*8*64);
      GLDS16(vth + vsrc, VhS + seg*8*64);
      GLDS16(vtl + vsrc, VlS + seg*8*64);
    }
    __syncthreads();

    f32x4 s[4];
    #pragma unroll
    for (int fj=0; fj<4; fj++) s[fj] = (f32x4){0.f,0.f,0.f,0.f};
    #pragma unroll
    for (int ks=0; ks<2; ks++){
      int chunk = ks*4 + l4;
      #pragma unroll
      for (int fj=0; fj<4; fj++){
        short8 bh = lds_swz(KhS, fj*16 + l15, chunk);
        short8 bl = lds_swz(KlS, fj*16 + l15, chunk);
        s[fj] = __builtin_amdgcn_mfma_f32_16x16x32_bf16(qh[ks], bh, s[fj], 0,0,0);
        s[fj] = __builtin_amdgcn_mfma_f32_16x16x32_bf16(ql[ks], bh, s[fj], 0,0,0);
        s[fj] = __builtin_amdgcn_mfma_f32_16x16x32_bf16(qh[ks], bl, s[fj], 0,0,0);
      }
    }

    if (causal && kt == qblk){
      #pragma unroll
      for (int fj=0; fj<4; fj++){
        int key = kt*64 + fj*16 + l15;
        #pragma unroll
        for (int reg=0; reg<4; reg++){
          int qr = qb0 + w*16 + l4*4 + reg;
          if (key > qr) s[fj][reg] = -3.0e38f;
        }
      }
    }

    float c[4], pmax[4];
    #pragma unroll
    for (int reg=0; reg<4; reg++){
      float mx = fmaxf(fmaxf(s[0][reg], s[1][reg]), fmaxf(s[2][reg], s[3][reg]));
      mx = fmaxf(mx, __shfl_xor(mx, 1));
      mx = fmaxf(mx, __shfl_xor(mx, 2));
      mx = fmaxf(mx, __shfl_xor(mx, 4));
      mx = fmaxf(mx, __shfl_xor(mx, 8));
      float mn = fmaxf(m[reg], mx);
      c[reg] = __expf(m[reg] - mn);
      m[reg] = mn;
      pmax[reg] = mn;
    }
    float psum[4] = {0.f,0.f,0.f,0.f};
    #pragma unroll
    for (int fj=0; fj<4; fj++){
      #pragma unroll
      for (int reg=0; reg<4; reg++){
        float pv = __expf(s[fj][reg] - pmax[reg]);
        psum[reg] += pv;
        Pp[w][(l4*4 + reg)*AT_LDP + fj*16 + l15] = splitbf_pack(pv);
      }
    }
    #pragma unroll
    for (int reg=0; reg<4; reg++){
      float ps = psum[reg];
      ps += __shfl_xor(ps, 1); ps += __shfl_xor(ps, 2);
      ps += __shfl_xor(ps, 4); ps += __shfl_xor(ps, 8);
      lsum[reg] = lsum[reg]*c[reg] + ps;
      o[0][reg] *= c[reg]; o[1][reg] *= c[reg];
      o[2][reg] *= c[reg]; o[3][reg] *= c[reg];
    }

    #pragma unroll
    for (int ks=0; ks<2; ks++){
      int chunk = ks*4 + l4;
      u32x4 pa = *(const u32x4*)&Pp[w][l15*AT_LDP + ks*32 + l4*8];
      u32x4 pb = *(const u32x4*)&Pp[w][l15*AT_LDP + ks*32 + l4*8 + 4];
      short8 ph, pl;
      #pragma unroll
      for (int j=0;j<4;j++){
        ph[j]   = (short)(pa[j] & 0xFFFFu); pl[j]   = (short)(pa[j] >> 16);
        ph[4+j] = (short)(pb[j] & 0xFFFFu); pl[4+j] = (short)(pb[j] >> 16);
      }
      #pragma unroll
      for (int fd=0; fd<4; fd++){
        short8 vh = lds_swz(VhS, fd*16 + l15, chunk);
        short8 vl = lds_swz(VlS, fd*16 + l15, chunk);
        o[fd] = __builtin_amdgcn_mfma_f32_16x16x32_bf16(ph, vh, o[fd], 0,0,0);
        o[fd] = __builtin_amdgcn_mfma_f32_16x16x32_bf16(pl, vh, o[fd], 0,0,0);
        o[fd] = __builtin_amdgcn_mfma_f32_16x16x32_bf16(ph, vl, o[fd], 0,0,0);
      }
    }
  }

  #pragma unroll
  for (int reg=0; reg<4; reg++){
    float inv = 1.0f / lsum[reg];
    long long tok = b*S_ + qb0 + w*16 + l4*4 + reg;
    #pragma unroll
    for (int fd=0; fd<4; fd++){
      unsigned int pk = splitbf_pack(o[fd][reg]*inv);
      long long oidx = tok*D_ + h*DH_ + fd*16 + l15;
      ctxh[oidx] = (unsigned short)(pk & 0xFFFFu);
      ctxl[oidx] = (unsigned short)(pk >> 16);
    }
  }
}

// ---------------- MoE gate ----------------
__global__ __launch_bounds__(256) void gate_kernel(const float* __restrict__ xnf,
                                                   const float* __restrict__ gw,
                                                   const float* __restrict__ gb,
                                                   int* __restrict__ counts,
                                                   int* __restrict__ toklist,
                                                   int* __restrict__ route_e,
                                                   int* __restrict__ route_pos,
                                                   float* __restrict__ route_w){
  int t = blockIdx.x*4 + (threadIdx.x >> 6);
  int lane = threadIdx.x & 63;
  float acc[E_];
  #pragma unroll
  for (int e=0;e<E_;e++) acc[e] = 0.f;
  #pragma unroll
  for (int i=0;i<12;i++){
    int d = lane + 64*i;
    float xv = xnf[(long long)t*D_ + d];
    const float* w = gw + (long long)d*E_;
    #pragma unroll
    for (int e=0;e<E_;e++) acc[e] += xv*w[e];
  }
  #pragma unroll
  for (int off=32; off; off>>=1)
    #pragma unroll
    for (int e=0;e<E_;e++) acc[e] += __shfl_xor(acc[e], off);
  if (lane == 0){
    #pragma unroll
    for (int e=0;e<E_;e++) acc[e] += gb[e];
    int e0 = 0;
    #pragma unroll
    for (int e=1;e<E_;e++) if (acc[e] > acc[e0]) e0 = e;
    int e1 = -1;
    #pragma unroll
    for (int e=0;e<E_;e++) if (e != e0 && (e1 < 0 || acc[e] > acc[e1])) e1 = e;
    float w0 = 1.0f/(1.0f + __expf(acc[e1] - acc[e0]));
    float w1 = 1.0f - w0;
    int p0 = atomicAdd(&counts[e0], 1);
    int p1 = atomicAdd(&counts[e1], 1);
    toklist[e0*NTOK + p0] = t;
    toklist[e1*NTOK + p1] = t;
    route_e[2*t]   = e0; route_e[2*t+1]   = e1;
    route_pos[2*t] = p0; route_pos[2*t+1] = p1;
    route_w[2*t]   = w0; route_w[2*t+1]   = w1;
  }
}

__global__ __launch_bounds__(192) void combine_kernel(const float* __restrict__ xb,
                                                      const float* __restrict__ y,
                                                      long long partStride,
                                                      const int* __restrict__ counts,
                                                      const int* __restrict__ route_e,
                                                      const int* __restrict__ route_pos,
                                                      const float* __restrict__ route_w,
                                                      float* __restrict__ out){
  int t = blockIdx.x;
  int i = threadIdx.x;
  int e0 = route_e[2*t], e1 = route_e[2*t+1];
  int off0 = 0, off1 = 0;
  for (int e=0;e<E_;e++){
    if (e < e0) off0 += counts[e];
    if (e < e1) off1 += counts[e];
  }
  long long s0 = off0 + route_pos[2*t];
  long long s1 = off1 + route_pos[2*t+1];
  float w0 = route_w[2*t], w1 = route_w[2*t+1];
  f32x4 xv = *(const f32x4*)(xb + (long long)t*D_ + i*4);
  f32x4 y0 = (f32x4){0.f,0.f,0.f,0.f};
  f32x4 y1 = (f32x4){0.f,0.f,0.f,0.f};
  #pragma unroll
  for (int kp=0; kp<2; kp++){
    y0 += *(const f32x4*)(y + kp*partStride + s0*D_ + i*4);
    y1 += *(const f32x4*)(y + kp*partStride + s1*D_ + i*4);
  }
  f32x4 o = xv + w0*y0 + w1*y1;
  *(f32x4*)(out + (long long)t*D_ + i*4) = o;
}

// ---------------- host orchestration ----------------
extern "C" void kernel_launch(void* const* d_in, const int* in_sizes, int n_in,
                              void* d_out, int out_size, void* d_ws, size_t ws_size,
                              hipStream_t stream) {
  (void)in_sizes; (void)n_in; (void)out_size; (void)ws_size;
  const float* x     = (const float*)d_in[0];
  const float* enc   = (const float*)d_in[1];
  const float* ln1s  = (const float*)d_in[2];
  const float* ln1b  = (const float*)d_in[3];
  const float* ln2s  = (const float*)d_in[4];
  const float* ln2b  = (const float*)d_in[5];
  const float* ln3s  = (const float*)d_in[6];
  const float* ln3b  = (const float*)d_in[7];
  const float* sa_wq = (const float*)d_in[8];
  const float* sa_bq = (const float*)d_in[9];
  const float* sa_wk = (const float*)d_in[10];
  const float* sa_bk = (const float*)d_in[11];
  const float* sa_wv = (const float*)d_in[12];
  const float* sa_bv = (const float*)d_in[13];
  const float* sa_wo = (const float*)d_in[14];
  const float* sa_bo = (const float*)d_in[15];
  const float* ca_wq = (const float*)d_in[16];
  const float* ca_bq = (const float*)d_in[17];
  const float* ca_wk = (const float*)d_in[18];
  const float* ca_bk = (const float*)d_in[19];
  const float* ca_wv = (const float*)d_in[20];
  const float* ca_bv = (const float*)d_in[21];
  const float* ca_wo = (const float*)d_in[22];
  const float* ca_bo = (const float*)d_in[23];
  const float* gate_w= (const float*)d_in[24];
  const float* gate_b= (const float*)d_in[25];
  const float* w1    = (const float*)d_in[26];
  const float* b1    = (const float*)d_in[27];
  const float* w2    = (const float*)d_in[28];
  const float* b2    = (const float*)d_in[29];
  float* out = (float*)d_out;

  char* p = (char*)d_ws;
  auto alloc = [&](size_t bytes)->void*{
    void* r = (void*)p;
    p += (bytes + 255) & ~(size_t)255;
    return r;
  };
  unsigned short* wqkvh_sa = (unsigned short*)alloc((size_t)1280*768*2);
  unsigned short* wqkvl_sa = (unsigned short*)alloc((size_t)1280*768*2);
  unsigned short* woh_sa   = (unsigned short*)alloc((size_t)768*768*2);
  unsigned short* wol_sa   = (unsigned short*)alloc((size_t)768*768*2);
  unsigned short* wqh_ca   = (unsigned short*)alloc((size_t)768*768*2);
  unsigned short* wql_ca   = (unsigned short*)alloc((size_t)768*768*2);
  unsigned short* wkvh_ca  = (unsigned short*)alloc((size_t)512*768*2);
  unsigned short* wkvl_ca  = (unsigned short*)alloc((size_t)512*768*2);
  unsigned short* woh_ca   = (unsigned short*)alloc((size_t)768*768*2);
  unsigned short* wol_ca   = (unsigned short*)alloc((size_t)768*768*2);
  unsigned short* w1T = (unsigned short*)alloc((size_t)E_*D_*F_*2);
  unsigned short* w2T = (unsigned short*)alloc((size_t)E_*D_*F_*2);
  float* bqkv_sa = (float*)alloc(1280*4);
  float* bkv_ca  = (float*)alloc(512*4);
  unsigned short* ench = (unsigned short*)alloc((size_t)NTOK*D_*2);
  unsigned short* encl = (unsigned short*)alloc((size_t)NTOK*D_*2);
  unsigned short* xh   = (unsigned short*)alloc((size_t)NTOK*D_*2);
  unsigned short* xl   = (unsigned short*)alloc((size_t)NTOK*D_*2);
  unsigned short* ctxh = (unsigned short*)alloc((size_t)NTOK*D_*2);
  unsigned short* ctxl = (unsigned short*)alloc((size_t)NTOK*D_*2);
  unsigned short* xn_b = (unsigned short*)alloc((size_t)NTOK*D_*2);
  unsigned short* hbuf = (unsigned short*)alloc((size_t)2*NTOK*F_*2);
  unsigned short* khp   = (unsigned short*)alloc((size_t)NTOK*G_*DH_*2);
  unsigned short* klp   = (unsigned short*)alloc((size_t)NTOK*G_*DH_*2);
  unsigned short* vtp_h = (unsigned short*)alloc((size_t)NTOK*G_*DH_*2);
  unsigned short* vtp_l = (unsigned short*)alloc((size_t)NTOK*G_*DH_*2);
  float* vbuf = (float*)alloc((size_t)NTOK*G_*DH_*4);
  float* qbuf = (float*)alloc((size_t)NTOK*D_*4);
  float* xnf  = (float*)alloc((size_t)NTOK*D_*4);
  float* xbuf = (float*)alloc((size_t)NTOK*D_*4);
  float* ybuf = (float*)alloc((size_t)4*NTOK*D_*4);
  int* counts    = (int*)alloc(E_*4);
  int* toklist   = (int*)alloc((size_t)E_*NTOK*4);
  int* route_e   = (int*)alloc((size_t)2*NTOK*4);
  int* route_pos = (int*)alloc((size_t)2*NTOK*4);
  float* route_w = (float*)alloc((size_t)2*NTOK*4);

  (void)hipMemsetAsync(counts, 0, E_*sizeof(int), stream);

  dim3 tb(32,8);
  {
    TC4 a;
    a.s[0]=sa_wq; a.h[0]=wqkvh_sa;           a.l[0]=wqkvl_sa;
    a.s[1]=sa_wo; a.h[1]=woh_sa;             a.l[1]=wol_sa;
    a.s[2]=ca_wq; a.h[2]=wqh_ca;             a.l[2]=wql_ca;
    a.s[3]=ca_wo; a.h[3]=woh_ca;             a.l[3]=wol_ca;
    tcast4_kernel<<<dim3(24,24,4), tb, 0, stream>>>(a, 768, 768);
    TC4 b;
    b.s[0]=sa_wk; b.h[0]=wqkvh_sa + 768*768;  b.l[0]=wqkvl_sa + 768*768;
    b.s[1]=sa_wv; b.h[1]=wqkvh_sa + 1024*768; b.l[1]=wqkvl_sa + 1024*768;
    b.s[2]=ca_wk; b.h[2]=wkvh_ca;             b.l[2]=wkvl_ca;
    b.s[3]=ca_wv; b.h[3]=wkvh_ca + 256*768;   b.l[3]=wkvl_ca + 256*768;
    tcast4_kernel<<<dim3(8,24,4), tb, 0, stream>>>(b, 768, 256);
  }
  tcast_kernel<<<dim3(96,24,E_), tb, 0, stream>>>(w1, w1T, nullptr, 768, 3072);
  tcast_kernel<<<dim3(24,96,E_), tb, 0, stream>>>(w2, w2T, nullptr, 3072, 768);
  concat_bias<<<5, 256, 0, stream>>>(sa_bq, 768, sa_bk, 256, sa_bv, 256, bqkv_sa);
  concat_bias<<<2, 256, 0, stream>>>(ca_bk, 256, ca_bv, 256, nullptr, 0, bkv_ca);
  split_rows<<<NTOK, 192, 0, stream>>>(enc, 768, 768, ench, encl);

  // ---- self-attention ----
  ln_kernel<<<NTOK, 256, 0, stream>>>(x, ln1s, ln1b, xh, xl, nullptr);
  gemm3<<<20*32, 256, 0, stream>>>(20, 20,
      xh, xl, 768, wqkvh_sa, wqkvl_sa, bqkv_sa,
      nullptr, nullptr, 0, nullptr, nullptr, nullptr,
      768, 1, nullptr, 0, nullptr, 0,
      qbuf, khp, klp, vbuf);
  vt_split_kernel<<<dim3(32,2,8), tb, 0, stream>>>(vbuf, vtp_h, vtp_l);
  attn_mfma<<<dim3(16,12,2), 256, 0, stream>>>(qbuf, 768, khp, klp, vtp_h, vtp_l, ctxh, ctxl, 1);
  gemm3<<<12*32, 256, 0, stream>>>(12, 12,
      ctxh, ctxl, 768, woh_sa, wol_sa, sa_bo,
      nullptr, nullptr, 0, nullptr, nullptr, nullptr,
      768, 0, x, 768, xbuf, 768,
      nullptr, nullptr, nullptr, nullptr);

  // ---- cross-attention ----
  ln_kernel<<<NTOK, 256, 0, stream>>>(xbuf, ln2s, ln2b, xh, xl, nullptr);
  gemm3<<<20*32, 256, 0, stream>>>(20, 12,
      xh, xl, 768, wqh_ca, wql_ca, ca_bq,
      ench, encl, 768, wkvh_ca, wkvl_ca, bkv_ca,
      768, 1, nullptr, 0, nullptr, 0,
      qbuf, khp, klp, vbuf);
  vt_split_kernel<<<dim3(32,2,8), tb, 0, stream>>>(vbuf, vtp_h, vtp_l);
  attn_mfma<<<dim3(16,12,2), 256, 0, stream>>>(qbuf, 768, khp, klp, vtp_h, vtp_l, ctxh, ctxl, 0);
  gemm3<<<12*32, 256, 0, stream>>>(12, 12,
      ctxh, ctxl, 768, woh_ca, wol_ca, ca_bo,
      nullptr, nullptr, 0, nullptr, nullptr, nullptr,
      768, 0, xbuf, 768, xbuf, 768,
      nullptr, nullptr, nullptr, nullptr);

  // ---- MoE ----
  ln_kernel<<<NTOK, 256, 0, stream>>>(xbuf, ln3s, ln3b, xn_b, nullptr, xnf);
  gate_kernel<<<NTOK/4, 256, 0, stream>>>(xnf, gate_w, gate_b,
      counts, toklist, route_e, route_pos, route_w);
  // w1: BM=128 BN=64, 48 panels x 16 m-blocks
  gemm_nt<128,64><<<48*16*E_, 256, 0, stream>>>(48, 1, xn_b, 768, w1T, (long long)F_*D_, b1, F_,
      counts, toklist, NTOK, nullptr, 0, hbuf, F_, 768, 1);
  // w2: BM=128 BN=64, 12 panels x 16 m-blocks, split-K x2
  long long partStride = (long long)2*NTOK*D_;
  gemm_nt<128,64><<<12*16*E_*2, 256, 0, stream>>>(12, 2, hbuf, F_, w2T, (long long)F_*D_, b2, D_,
      counts, nullptr, 0, ybuf, partStride, nullptr, 768, F_, 0);
  combine_kernel<<<NTOK, 192, 0, stream>>>(xbuf, ybuf, partStride,
      counts, route_e, route_pos, route_w, out);
}